// Round 4
// baseline (1067.593 us; speedup 1.0000x reference)
//
#include <hip/hip_runtime.h>
#include <hip/hip_bf16.h>
#include <hip/hip_fp16.h>

// tanh-RNN + FC on MI355X.
// conv_w -> gemm_xproj (f16 MFMA, scan-native xp layout, XCD-grouped grid) ->
// rnn_scan4 (32 blocks x 256 thr, 1 wave/SIMD @ 512 VGPR: 6/8 W-tiles pinned
// in VGPRs, 2/8 L2-streamed; h in k8-major LDS; rnn_out via LDS transpose) ->
// gemm_logits (in-place over d_out).

typedef _Float16 half8 __attribute__((ext_vector_type(8)));
typedef _Float16 half4 __attribute__((ext_vector_type(4)));
typedef float f32x4 __attribute__((ext_vector_type(4)));

// ws layout (bytes)
#define XPW_OFF   0UL            // 64MB x_proj f16 (scan-native layout)
#define WIH_OFF   67108864UL     // 512KB f16 W_ih
#define FCW_OFF   67633152UL     // 256KB f16 fc_w
#define BIAS_OFF  67895296UL     // 2KB f32 bias2
#define WRES_OFF  67897344UL     // 384KB resident W frags [w(4)][f(96)][lane(64)][8]
#define WSTR_OFF  68290560UL     // 128KB streamed W frags [w(4)][g(32)][lane(64)][8]

// ---------------------------------------------------------------------------
// conv_w: f16 copies of W_ih, fc_w; bias2 = b_ih + b_hh; W_hh pre-swizzled
// into wres (resident frags, n=0..5) and wstr (streamed frags, n=6..7).
// ---------------------------------------------------------------------------
__global__ void conv_w(const float* __restrict__ Wih, const float* __restrict__ Whh,
                       const float* __restrict__ fcw, const float* __restrict__ bih,
                       const float* __restrict__ bhh,
                       _Float16* __restrict__ wih_h, _Float16* __restrict__ fcw_h,
                       float* __restrict__ bias2,
                       _Float16* __restrict__ wres, _Float16* __restrict__ wstr) {
    int idx = blockIdx.x * 256 + threadIdx.x;
    if (idx < 262144) wih_h[idx] = (_Float16)Wih[idx];
    if (idx < 131072) fcw_h[idx] = (_Float16)fcw[idx];
    if (idx < 512) bias2[idx] = bih[idx] + bhh[idx];
    if (idx < 196608) {   // wres: [w][f=n*16+s][lane][i]
        const int i = idx & 7, l = (idx >> 3) & 63;
        const int wfid = idx >> 9;          // w*96 + f
        const int w = wfid / 96, f = wfid % 96;
        const int n = f >> 4, s = f & 15;
        wres[idx] = (_Float16)Whh[(size_t)(w * 128 + n * 16 + (l & 15)) * 512 + s * 32 + (l >> 4) * 8 + i];
    }
    if (idx < 65536) {    // wstr: [w][g=s*2+tile][lane][i], tile = n-6
        const int i = idx & 7, l = (idx >> 3) & 63;
        const int g = (idx >> 9) & 31, w = idx >> 14;
        wstr[idx] = (_Float16)Whh[(size_t)(w * 128 + 96 + (g & 1) * 16 + (l & 15)) * 512 + (g >> 1) * 32 + (l >> 4) * 8 + i];
    }
}

// ---------------------------------------------------------------------------
// K1: x_proj = states @ W_ih^T + bias2, stored in scan-native layout:
//   xps[(bg*128+t)*8192 + sw*2048 + skg*512 + sln*32 + sq*8 + sn]
//   where b = bg*16 + skg*4 + sq (batch), col = sw*128 + sn*16 + sln.
// Grid XCD-swizzled so the 4 blocks with b-low 0..3 (same cache lines in the
// sq-interleaved layout, same B-panel) land on one XCD.
// ---------------------------------------------------------------------------
__global__ __launch_bounds__(256) void gemm_xproj(const float* __restrict__ A,
                                                  const _Float16* __restrict__ Bw,
                                                  const float* __restrict__ bias2,
                                                  _Float16* __restrict__ out) {
    __shared__ _Float16 As[128 * 32];
    __shared__ _Float16 Bs[128 * 32];
    const int tid = threadIdx.x;
    // XCD-grouped bijective mapping: s -> (b, nq)
    const int s_ = blockIdx.x;
    const int z = s_ & 7, kk = s_ >> 3;
    const int blow = kk & 3;
    const int gq = z * 64 + (kk >> 2);     // 0..511
    const int gp = gq >> 2, nq = gq & 3;   // gp 0..127
    const int b = gp * 4 + blow;           // 0..511
    const int m0 = b << 7;                 // 128 rows = all t of batch b
    const int n0 = nq << 7;
    const int lane = tid & 63, w = tid >> 6;
    const int wr = (w >> 1) * 64, wc = (w & 1) * 64;
    const int ln = lane & 15, kg = lane >> 4;

    f32x4 acc[4][4];
#pragma unroll
    for (int m = 0; m < 4; m++)
#pragma unroll
        for (int n = 0; n < 4; n++) acc[m][n] = (f32x4)0.0f;

    const int sr = tid >> 1;
    const int sc = (tid & 1) * 16;

    for (int k0 = 0; k0 < 512; k0 += 32) {
        {
            const float* ga = A + (size_t)(m0 + sr) * 512 + k0 + sc;
            float4 f0 = *(const float4*)(ga + 0);
            float4 f1 = *(const float4*)(ga + 4);
            float4 f2 = *(const float4*)(ga + 8);
            float4 f3 = *(const float4*)(ga + 12);
            half8 h0, h1;
            h0[0] = (_Float16)f0.x; h0[1] = (_Float16)f0.y; h0[2] = (_Float16)f0.z; h0[3] = (_Float16)f0.w;
            h0[4] = (_Float16)f1.x; h0[5] = (_Float16)f1.y; h0[6] = (_Float16)f1.z; h0[7] = (_Float16)f1.w;
            h1[0] = (_Float16)f2.x; h1[1] = (_Float16)f2.y; h1[2] = (_Float16)f2.z; h1[3] = (_Float16)f2.w;
            h1[4] = (_Float16)f3.x; h1[5] = (_Float16)f3.y; h1[6] = (_Float16)f3.z; h1[7] = (_Float16)f3.w;
            *(half8*)&As[sr * 32 + sc] = h0;
            *(half8*)&As[sr * 32 + sc + 8] = h1;
        }
        {
            const _Float16* gb = Bw + (size_t)(n0 + sr) * 512 + k0 + sc;
            *(half8*)&Bs[sr * 32 + sc] = *(const half8*)(gb);
            *(half8*)&Bs[sr * 32 + sc + 8] = *(const half8*)(gb + 8);
        }
        __syncthreads();
        half8 af[4], bf[4];
#pragma unroll
        for (int m = 0; m < 4; m++) af[m] = *(const half8*)&As[(wr + m * 16 + ln) * 32 + kg * 8];
#pragma unroll
        for (int n = 0; n < 4; n++) bf[n] = *(const half8*)&Bs[(wc + n * 16 + ln) * 32 + kg * 8];
#pragma unroll
        for (int m = 0; m < 4; m++)
#pragma unroll
            for (int n = 0; n < 4; n++)
                acc[m][n] = __builtin_amdgcn_mfma_f32_16x16x32_f16(af[m], bf[n], acc[m][n], 0, 0, 0);
        __syncthreads();
    }
    // epilogue: 16x 8B stores into scan-native layout
    const int bg2 = b >> 4, skg2 = (b >> 2) & 3, sq2 = b & 3;
    const int sw = (n0 + wc) >> 7;
    const int snb = ((n0 + wc) >> 4) & 7;   // 0 or 4
    float bv[4];
#pragma unroll
    for (int n = 0; n < 4; n++) bv[n] = bias2[n0 + wc + n * 16 + ln];
    const size_t tb = (size_t)(bg2 * 128) * 8192 + (size_t)sw * 2048 + skg2 * 512
                    + (size_t)ln * 32 + sq2 * 8 + snb;
#pragma unroll
    for (int m = 0; m < 4; m++)
#pragma unroll
        for (int q = 0; q < 4; q++) {
            half4 v;
#pragma unroll
            for (int n = 0; n < 4; n++) v[n] = (_Float16)(acc[m][n][q] + bv[n]);
            const int t = wr + m * 16 + kg * 4 + q;
            *(half4*)&out[tb + (size_t)t * 8192] = v;
        }
}

// ---------------------------------------------------------------------------
// Scan v4: 32 blocks x 256 threads (4 waves, 1/SIMD, 512 VGPR budget).
// Wave w owns j in [w*128, w*128+128): n-tiles 0..5 resident in VGPRs (384
// regs, pinned), tiles 6..7 streamed from L2 (depth-8 rolling prefetch).
// h(t) in k8-major LDS hb; unmasked h through hb2 -> coalesced rnn stores.
// ---------------------------------------------------------------------------
__global__ __launch_bounds__(256, 1) void rnn_scan4(
    const _Float16* __restrict__ xps,
    const _Float16* __restrict__ wres,
    const _Float16* __restrict__ wstr,
    const int* __restrict__ term,
    const float* __restrict__ h0,
    float* dout) {
    __shared__ __align__(16) _Float16 hb[8192];        // k8-major masked h
    __shared__ __align__(16) _Float16 hb2[16 * 524];   // row-major unmasked h (stride 524)
    __shared__ unsigned int term_lds[16][4];
    const int tid = threadIdx.x;
    const int bg = blockIdx.x;
    const int R0 = bg * 16;
    const int lane = tid & 63, w = tid >> 6;
    const int ln = lane & 15, kg = lane >> 4;
    _Float16* rnn = (_Float16*)dout;

    // ---- resident weights (coalesced from wres), pinned ----
    half8 wf[96];
    {
        const _Float16* wp = wres + ((size_t)w * 96 * 64 + lane) * 8;
#pragma unroll
        for (int f = 0; f < 96; f++) wf[f] = *(const half8*)(wp + f * 512);
    }
#pragma unroll
    for (int f = 0; f < 96; f++) asm volatile("" : "+v"(wf[f]));

    // ---- h0 -> hb (f32 -> f16, k8-major) ----
    {
        const int r = tid >> 4, c0 = (tid & 15) * 32;
        const float* gh = h0 + (size_t)(R0 + r) * 512 + c0;
#pragma unroll
        for (int u = 0; u < 4; u++) {
            half8 v;
#pragma unroll
            for (int i = 0; i < 8; i++) v[i] = (_Float16)gh[u * 8 + i];
            *(half8*)&hb[((c0 >> 3) + u) * 128 + r * 8] = v;
        }
    }
    // ---- termination bitmasks ----
    if (tid < 64) {
        const int r = tid >> 2, word = tid & 3;
        unsigned int m = 0;
        for (int b2 = 0; b2 < 32; b2++)
            m |= (term[(R0 + r) * 128 + word * 32 + b2] ? 1u : 0u) << b2;
        term_lds[r][word] = m;
    }
    __syncthreads();

    // ---- streamed-frag rolling buffer (depth 8) ----
    const _Float16* wsb = wstr + (size_t)w * 16384;
    half8 wst[8];
#pragma unroll
    for (int p = 0; p < 8; p++) wst[p] = *(const half8*)(wsb + p * 512 + lane * 8);

    unsigned int tmask[4];
#pragma unroll 1
    for (int t = 0; t < 128; ++t) {
        if ((t & 31) == 0) {
#pragma unroll
            for (int q = 0; q < 4; q++) tmask[q] = term_lds[kg * 4 + q][t >> 5];
        }
        // xp: 64B contiguous per thread, [q][n] packed
        const _Float16* xpp = xps + (size_t)(bg * 128 + t) * 8192 + w * 2048 + kg * 512 + ln * 32;
        half8 xv[4];
#pragma unroll
        for (int u = 0; u < 4; u++) xv[u] = *(const half8*)(xpp + u * 8);

        f32x4 acc[8];
#pragma unroll
        for (int n = 0; n < 8; n++) acc[n] = (f32x4)0.0f;

#pragma unroll
        for (int s = 0; s < 16; s++) {
            const half8 a = *(const half8*)&hb[(s * 4 + kg) * 128 + ln * 8];
            acc[0] = __builtin_amdgcn_mfma_f32_16x16x32_f16(a, wf[s],      acc[0], 0, 0, 0);
            acc[1] = __builtin_amdgcn_mfma_f32_16x16x32_f16(a, wf[16 + s], acc[1], 0, 0, 0);
            acc[2] = __builtin_amdgcn_mfma_f32_16x16x32_f16(a, wf[32 + s], acc[2], 0, 0, 0);
            acc[3] = __builtin_amdgcn_mfma_f32_16x16x32_f16(a, wf[48 + s], acc[3], 0, 0, 0);
            acc[4] = __builtin_amdgcn_mfma_f32_16x16x32_f16(a, wf[64 + s], acc[4], 0, 0, 0);
            acc[5] = __builtin_amdgcn_mfma_f32_16x16x32_f16(a, wf[80 + s], acc[5], 0, 0, 0);
            acc[6] = __builtin_amdgcn_mfma_f32_16x16x32_f16(a, wst[(2 * s) & 7],     acc[6], 0, 0, 0);
            acc[7] = __builtin_amdgcn_mfma_f32_16x16x32_f16(a, wst[(2 * s + 1) & 7], acc[7], 0, 0, 0);
            // refill just-consumed slots (wraps into next step's frags 0..7)
            wst[(2 * s) & 7]     = *(const half8*)(wsb + ((2 * s + 8) & 31) * 512 + lane * 8);
            wst[(2 * s + 1) & 7] = *(const half8*)(wsb + ((2 * s + 9) & 31) * 512 + lane * 8);
        }
        __syncthreads();   // all hb reads of h(t) done

        // tanh; unmasked -> hb2, masked -> hb
#pragma unroll
        for (int n = 0; n < 8; n++)
#pragma unroll
            for (int q = 0; q < 4; q++) {
                const float pre = acc[n][q] + (float)xv[q][n];
                const float e = __expf(2.0f * pre);
                const float hn = 1.0f - 2.0f / (e + 1.0f);
                const _Float16 hh = (_Float16)hn;
                const int col = w * 128 + n * 16 + ln;
                hb2[(kg * 4 + q) * 524 + col] = hh;
                hb[(col >> 3) * 128 + (kg * 4 + q) * 8 + (col & 7)] =
                    ((tmask[q] >> (t & 31)) & 1) ? (_Float16)0.0f : hh;
            }
        __syncthreads();   // hb2/hb complete

        // rnn_out store: LDS-transposed, coalesced 16B global stores
        {
            const int r2 = tid & 15, ch = tid >> 4;
            const _Float16* hrow = &hb2[r2 * 524 + ch * 32];
            uint2 a0 = *(const uint2*)(hrow + 0);
            uint2 a1 = *(const uint2*)(hrow + 4);
            uint2 a2 = *(const uint2*)(hrow + 8);
            uint2 a3 = *(const uint2*)(hrow + 12);
            uint2 a4 = *(const uint2*)(hrow + 16);
            uint2 a5 = *(const uint2*)(hrow + 20);
            uint2 a6 = *(const uint2*)(hrow + 24);
            uint2 a7 = *(const uint2*)(hrow + 28);
            _Float16* gp = rnn + ((size_t)(R0 + r2) * 128 + t) * 512 + ch * 32;
            *(uint4*)(gp + 0)  = uint4{a0.x, a0.y, a1.x, a1.y};
            *(uint4*)(gp + 8)  = uint4{a2.x, a2.y, a3.x, a3.y};
            *(uint4*)(gp + 16) = uint4{a4.x, a4.y, a5.x, a5.y};
            *(uint4*)(gp + 24) = uint4{a6.x, a6.y, a7.x, a7.y};
        }
    }

    // ---- h_final (masked h(128)) -> f32 at d_out + 65536*256 ----
    {
        const int r = tid >> 4, c0 = (tid & 15) * 32;
        float* gf = dout + (size_t)65536 * 256 + (size_t)(R0 + r) * 512 + c0;
#pragma unroll
        for (int u = 0; u < 4; u++) {
            half8 v = *(const half8*)&hb[((c0 >> 3) + u) * 128 + r * 8];
#pragma unroll
            for (int i = 0; i < 8; i++) gf[u * 8 + i] = (float)v[i];
        }
    }
}

// ---------------------------------------------------------------------------
// K3: logits[65536,256] (f32) = rnn_out(f16, in d_out) @ fc_w^T + fc_b
// ---------------------------------------------------------------------------
__global__ __launch_bounds__(512) void gemm_logits(const _Float16* Arnn,
                                                   const _Float16* __restrict__ Bw,
                                                   const float* __restrict__ biasv,
                                                   float* out) {
    __shared__ _Float16 As[128 * 32];
    __shared__ _Float16 Bs[256 * 32];
    const int tid = threadIdx.x;
    const int m0 = blockIdx.x * 128;
    const int lane = tid & 63, w = tid >> 6;
    const int wr = (w >> 2) * 64, wc = (w & 3) * 64;
    const int ln = lane & 15, kg = lane >> 4;

    f32x4 acc[4][4];
#pragma unroll
    for (int m = 0; m < 4; m++)
#pragma unroll
        for (int n = 0; n < 4; n++) acc[m][n] = (f32x4)0.0f;

    const int ar = tid >> 2, ac = (tid & 3) * 8;
    const int br = tid >> 1, bc = (tid & 1) * 16;

    for (int k0 = 0; k0 < 512; k0 += 32) {
        *(half8*)&As[ar * 32 + ac] = *(const half8*)(Arnn + (size_t)(m0 + ar) * 512 + k0 + ac);
        {
            const _Float16* gb = Bw + (size_t)br * 512 + k0 + bc;
            *(half8*)&Bs[br * 32 + bc] = *(const half8*)(gb);
            *(half8*)&Bs[br * 32 + bc + 8] = *(const half8*)(gb + 8);
        }
        __syncthreads();
        half8 af[4], bf[4];
#pragma unroll
        for (int m = 0; m < 4; m++) af[m] = *(const half8*)&As[(wr + m * 16 + ln) * 32 + kg * 8];
#pragma unroll
        for (int n = 0; n < 4; n++) bf[n] = *(const half8*)&Bs[(wc + n * 16 + ln) * 32 + kg * 8];
#pragma unroll
        for (int m = 0; m < 4; m++)
#pragma unroll
            for (int n = 0; n < 4; n++)
                acc[m][n] = __builtin_amdgcn_mfma_f32_16x16x32_f16(af[m], bf[n], acc[m][n], 0, 0, 0);
        __syncthreads();
    }
#pragma unroll
    for (int m = 0; m < 4; m++)
#pragma unroll
        for (int n = 0; n < 4; n++) {
            const int col = wc + n * 16 + ln;
            const float bv = biasv[col];
#pragma unroll
            for (int q = 0; q < 4; q++) {
                const int row = m0 + wr + m * 16 + kg * 4 + q;
                out[(size_t)row * 256 + col] = acc[m][n][q] + bv;
            }
        }
}

// ---------------------------------------------------------------------------
extern "C" void kernel_launch(void* const* d_in, const int* in_sizes, int n_in,
                              void* d_out, int out_size, void* d_ws, size_t ws_size,
                              hipStream_t stream) {
    const float* states = (const float*)d_in[0];
    const int*   term   = (const int*)d_in[1];
    const float* h0     = (const float*)d_in[2];
    const float* Wih    = (const float*)d_in[3];
    const float* Whh    = (const float*)d_in[4];
    const float* bih    = (const float*)d_in[5];
    const float* bhh    = (const float*)d_in[6];
    const float* fcw    = (const float*)d_in[7];
    const float* fcb    = (const float*)d_in[8];

    char* ws = (char*)d_ws;
    _Float16* xpw   = (_Float16*)(ws + XPW_OFF);
    _Float16* wih_h = (_Float16*)(ws + WIH_OFF);
    _Float16* fcw_h = (_Float16*)(ws + FCW_OFF);
    float*    bias2 = (float*)(ws + BIAS_OFF);
    _Float16* wres  = (_Float16*)(ws + WRES_OFF);
    _Float16* wstr  = (_Float16*)(ws + WSTR_OFF);

    conv_w<<<1024, 256, 0, stream>>>(Wih, Whh, fcw, bih, bhh, wih_h, fcw_h, bias2, wres, wstr);
    gemm_xproj<<<2048, 256, 0, stream>>>(states, wih_h, bias2, xpw);
    rnn_scan4<<<32, 256, 0, stream>>>(xpw, wres, wstr, term, h0, (float*)d_out);
    gemm_logits<<<512, 512, 0, stream>>>((const _Float16*)d_out, fcw_h, fcb, (float*)d_out);
}